// Round 7
// baseline (53.713 us; speedup 1.0000x reference)
//
#include <hip/hip_runtime.h>

#define NDESC 384
#define NTYPES 4
#define BLOCK_ATOMS 256
#define NTHREADS 384

typedef unsigned int uint32;
typedef unsigned long long u64;
typedef float f4 __attribute__((ext_vector_type(4)));

// tanh(x) = 1 - 2/(1+e^{2x}); native v_exp_f32 + v_rcp_f32. Abs err ~1e-6.
__device__ __forceinline__ float fast_tanh(float x) {
  float e = __builtin_amdgcn_exp2f(x * 2.8853900817779268f);   // e^{2x}
  return 1.0f - 2.0f * __builtin_amdgcn_rcpf(1.0f + e);
}

// ---------------- Kernel 1: per-block type histogram (ballot-based) --------
__global__ __launch_bounds__(BLOCK_ATOMS) void hist_kernel(
    const int* __restrict__ types, uint32* __restrict__ blockHist, int n) {
  __shared__ uint32 waveCnt[BLOCK_ATOMS / 64][NTYPES];
  int tid = threadIdx.x;
  int idx = blockIdx.x * BLOCK_ATOMS + tid;
  int ty = (idx < n) ? types[idx] : -1;
  int wave = tid >> 6, lane = tid & 63;
  for (int t = 0; t < NTYPES; ++t) {
    u64 m = __ballot(ty == t);
    if (lane == 0) waveCnt[wave][t] = (uint32)__popcll(m);
  }
  __syncthreads();
  if (tid < NTYPES) {
    uint32 s = 0;
    for (int w = 0; w < BLOCK_ATOMS / 64; ++w) s += waveCnt[w][tid];
    blockHist[blockIdx.x * NTYPES + tid] = s;
  }
}

// ---------------- Kernel 2: fused scan + rank + descriptor + scatter -------
// Each block scans blockHist itself (8 KB, L2-hot). Phase C iterates in RANK
// order (type-major): per block, 4 contiguous ~96 KB write segments. Stores
// are nontemporal (bypass L2 allocation — lines are never re-read).
__global__ __launch_bounds__(NTHREADS) void main_kernel(
    const float* __restrict__ coords, const int* __restrict__ types,
    const float* __restrict__ W, const uint32* __restrict__ blockHist,
    float* __restrict__ descOut, float* __restrict__ confOut,
    float* __restrict__ countsOut, int n, int nb) {
  __shared__ float sW[3 * NDESC];
  __shared__ float sC[BLOCK_ATOMS][3];
  __shared__ uint32 sRankPos[BLOCK_ATOMS];   // block-rank -> global position
  __shared__ uint32 sRankAtom[BLOCK_ATOMS];  // block-rank -> atom tid
  __shared__ uint32 waveCnt[BLOCK_ATOMS / 64][NTYPES];
  __shared__ uint32 sTot[NTYPES];   // global per-type totals
  __shared__ uint32 sOff[NTYPES];   // this block's global base per type
  __shared__ uint32 sCum[NTYPES];   // within-block exclusive type prefix

  int tid = threadIdx.x;
  int bid = blockIdx.x;
  int base = bid * BLOCK_ATOMS;

  // stage W (3x384) and this block's coords (256x3)
  for (int i = tid; i < 3 * NDESC; i += NTHREADS) sW[i] = W[i];
  for (int i = tid; i < BLOCK_ATOMS * 3; i += NTHREADS) {
    int g = base * 3 + i;
    sC[i / 3][i % 3] = (g < n * 3) ? coords[g] : 0.0f;
  }

  // ---- ballots: within-block per-wave counts + per-lane stable rank ----
  int idx = base + tid;
  int ty = -1;
  if (tid < BLOCK_ATOMS && idx < n) ty = types[idx];
  int wave = tid >> 6, lane = tid & 63;
  int myrank = 0;
  if (tid < BLOCK_ATOMS) {
    for (int t = 0; t < NTYPES; ++t) {
      u64 m = __ballot(ty == t);
      if (lane == 0) waveCnt[wave][t] = (uint32)__popcll(m);
      if (t == ty) myrank = (int)__popcll(m & ((1ull << lane) - 1ull));
    }
  }

  // ---- per-block scan of blockHist: wave t handles type t ----
  if (wave < NTYPES) {
    int t = wave;
    uint32 tot = 0, pre = 0;
    for (int b = lane; b < nb; b += 64) {
      uint32 h = blockHist[b * NTYPES + t];
      tot += h;
      if (b < bid) pre += h;
    }
    for (int off = 32; off > 0; off >>= 1) {
      tot += __shfl_down(tot, off);
      pre += __shfl_down(pre, off);
    }
    if (lane == 0) { sTot[t] = tot; sOff[t] = pre; }
  }
  __syncthreads();
  if (tid == 0) {
    uint32 b = 0, c = 0;
    for (int t = 0; t < NTYPES; ++t) {
      sOff[t] += b;
      b += sTot[t];
      uint32 cnt = 0;
      for (int w = 0; w < BLOCK_ATOMS / 64; ++w) cnt += waveCnt[w][t];
      sCum[t] = c;
      c += cnt;
    }
  }
  if (bid == 0 && tid < NTYPES) countsOut[tid] = (float)sTot[tid];
  __syncthreads();

  // ---- scatter rank tables + conf ids ----
  if (tid < BLOCK_ATOMS && ty >= 0) {
    uint32 fullrank = (uint32)myrank;
    for (int w = 0; w < wave; ++w) fullrank += waveCnt[w][ty];
    uint32 pos = sOff[ty] + fullrank;
    uint32 brk = sCum[ty] + fullrank;   // rank within block, 0..valid-1
    sRankPos[brk] = pos;
    sRankAtom[brk] = (uint32)tid;
    confOut[pos] = (float)(idx >> 6);   // idx / 64 atoms-per-conf
  }
  __syncthreads();

  // ---- phase C: rank order, 4 ranks x 96 threads, NT float4 stores ----
  int r = tid / 96;        // rank slot 0..3
  int c = tid - r * 96;    // 0..95
  int d0 = 4 * c;
  float w00 = sW[d0], w01 = sW[d0 + 1], w02 = sW[d0 + 2], w03 = sW[d0 + 3];
  float w10 = sW[NDESC + d0], w11 = sW[NDESC + d0 + 1],
        w12 = sW[NDESC + d0 + 2], w13 = sW[NDESC + d0 + 3];
  float w20 = sW[2 * NDESC + d0], w21 = sW[2 * NDESC + d0 + 1],
        w22 = sW[2 * NDESC + d0 + 2], w23 = sW[2 * NDESC + d0 + 3];

  int valid = n - base;
  if (valid > BLOCK_ATOMS) valid = BLOCK_ATOMS;

  if (valid == BLOCK_ATOMS) {
#pragma unroll 8
    for (int k0 = 0; k0 < BLOCK_ATOMS; k0 += 4) {
      int k = k0 + r;
      uint32 a = sRankAtom[k];
      uint32 pos = sRankPos[k];
      float c0 = sC[a][0], c1 = sC[a][1], c2 = sC[a][2];
      f4 v;
      v.x = fast_tanh(c0 * w00 + c1 * w10 + c2 * w20);
      v.y = fast_tanh(c0 * w01 + c1 * w11 + c2 * w21);
      v.z = fast_tanh(c0 * w02 + c1 * w12 + c2 * w22);
      v.w = fast_tanh(c0 * w03 + c1 * w13 + c2 * w23);
      __builtin_nontemporal_store(
          v, reinterpret_cast<f4*>(descOut + (size_t)pos * NDESC + d0));
    }
  } else {
    for (int k0 = 0; k0 < BLOCK_ATOMS; k0 += 4) {
      int k = k0 + r;
      if (k < valid) {
        uint32 a = sRankAtom[k];
        uint32 pos = sRankPos[k];
        float c0 = sC[a][0], c1 = sC[a][1], c2 = sC[a][2];
        f4 v;
        v.x = fast_tanh(c0 * w00 + c1 * w10 + c2 * w20);
        v.y = fast_tanh(c0 * w01 + c1 * w11 + c2 * w21);
        v.z = fast_tanh(c0 * w02 + c1 * w12 + c2 * w22);
        v.w = fast_tanh(c0 * w03 + c1 * w13 + c2 * w23);
        __builtin_nontemporal_store(
            v, reinterpret_cast<f4*>(descOut + (size_t)pos * NDESC + d0));
      }
    }
  }
}

extern "C" void kernel_launch(void* const* d_in, const int* in_sizes, int n_in,
                              void* d_out, int out_size, void* d_ws, size_t ws_size,
                              hipStream_t stream) {
  const float* coords = (const float*)d_in[0];
  const int* types = (const int*)d_in[1];
  const float* W = (const float*)d_in[2];

  int n = in_sizes[1];                      // total atoms (= n_confs * 64)
  int nb = (n + BLOCK_ATOMS - 1) / BLOCK_ATOMS;

  uint32* blockHist = (uint32*)d_ws;        // nb * 4 uints

  float* descOut = (float*)d_out;
  float* confOut = descOut + (size_t)n * NDESC;
  float* countsOut = confOut + n;

  hipLaunchKernelGGL(hist_kernel, dim3(nb), dim3(BLOCK_ATOMS), 0, stream,
                     types, blockHist, n);
  hipLaunchKernelGGL(main_kernel, dim3(nb), dim3(NTHREADS), 0, stream,
                     coords, types, W, blockHist, descOut, confOut, countsOut,
                     n, nb);
}

// Round 8
// 48.392 us; speedup vs baseline: 1.1100x; 1.1100x over previous
//
#include <hip/hip_runtime.h>

#define NDESC 384
#define NTYPES 4
#define BLOCK_ATOMS 256
#define NTHREADS 384
#define ROWS 64   // output rows per block in the gather kernel

typedef unsigned int uint32;
typedef unsigned long long u64;
typedef float f4 __attribute__((ext_vector_type(4)));

// tanh(x) = 1 - 2/(1+e^{2x}); native v_exp_f32 + v_rcp_f32. Abs err ~1e-6.
__device__ __forceinline__ float fast_tanh(float x) {
  float e = __builtin_amdgcn_exp2f(x * 2.8853900817779268f);   // e^{2x}
  return 1.0f - 2.0f * __builtin_amdgcn_rcpf(1.0f + e);
}

// ---------------- Kernel 1: per-block type histogram (ballot-based) --------
__global__ __launch_bounds__(BLOCK_ATOMS) void hist_kernel(
    const int* __restrict__ types, uint32* __restrict__ blockHist, int n) {
  __shared__ uint32 waveCnt[BLOCK_ATOMS / 64][NTYPES];
  int tid = threadIdx.x;
  int idx = blockIdx.x * BLOCK_ATOMS + tid;
  int ty = (idx < n) ? types[idx] : -1;
  int wave = tid >> 6, lane = tid & 63;
  for (int t = 0; t < NTYPES; ++t) {
    u64 m = __ballot(ty == t);
    if (lane == 0) waveCnt[wave][t] = (uint32)__popcll(m);
  }
  __syncthreads();
  if (tid < NTYPES) {
    uint32 s = 0;
    for (int w = 0; w < BLOCK_ATOMS / 64; ++w) s += waveCnt[w][tid];
    blockHist[blockIdx.x * NTYPES + tid] = s;
  }
}

// ---------------- Kernel 2: scan + rank -> inverse permutation -------------
// Each block scans blockHist itself (8 KB, L2-hot), computes each atom's
// global sorted position, writes perm[pos] = atom index. Also counts.
__global__ __launch_bounds__(BLOCK_ATOMS) void perm_kernel(
    const int* __restrict__ types, const uint32* __restrict__ blockHist,
    uint32* __restrict__ perm, float* __restrict__ countsOut, int n, int nb) {
  __shared__ uint32 waveCnt[BLOCK_ATOMS / 64][NTYPES];
  __shared__ uint32 sTot[NTYPES];
  __shared__ uint32 sOff[NTYPES];

  int tid = threadIdx.x;
  int bid = blockIdx.x;
  int base = bid * BLOCK_ATOMS;
  int idx = base + tid;
  int ty = (idx < n) ? types[idx] : -1;
  int wave = tid >> 6, lane = tid & 63;
  int myrank = 0;
  for (int t = 0; t < NTYPES; ++t) {
    u64 m = __ballot(ty == t);
    if (lane == 0) waveCnt[wave][t] = (uint32)__popcll(m);
    if (t == ty) myrank = (int)__popcll(m & ((1ull << lane) - 1ull));
  }

  // wave t scans blockHist for type t
  if (wave < NTYPES) {
    int t = wave;
    uint32 tot = 0, pre = 0;
    for (int b = lane; b < nb; b += 64) {
      uint32 h = blockHist[b * NTYPES + t];
      tot += h;
      if (b < bid) pre += h;
    }
    for (int off = 32; off > 0; off >>= 1) {
      tot += __shfl_down(tot, off);
      pre += __shfl_down(pre, off);
    }
    if (lane == 0) { sTot[t] = tot; sOff[t] = pre; }
  }
  __syncthreads();
  if (tid == 0) {
    uint32 b = 0;
    for (int t = 0; t < NTYPES; ++t) { sOff[t] += b; b += sTot[t]; }
  }
  if (bid == 0 && tid < NTYPES) countsOut[tid] = (float)sTot[tid];
  __syncthreads();

  if (ty >= 0) {
    uint32 fullrank = (uint32)myrank;
    for (int w = 0; w < wave; ++w) fullrank += waveCnt[w][ty];
    perm[sOff[ty] + fullrank] = (uint32)idx;
  }
}

// ---------------- Kernel 3: gather + compute + LINEAR stream write ---------
// Block b owns output rows [b*ROWS, b*ROWS+ROWS): reads perm (coalesced),
// gathers coords (near-sequential within type partitions), writes 98 KB
// contiguous. 4 rows x 96 threads, plain float4 stores, unroll 4.
__global__ __launch_bounds__(NTHREADS) void gather_kernel(
    const float* __restrict__ coords, const uint32* __restrict__ perm,
    const float* __restrict__ W, float* __restrict__ descOut,
    float* __restrict__ confOut, int n) {
  __shared__ float sW[3 * NDESC];
  __shared__ float sC[ROWS][3];
  __shared__ uint32 sPerm[ROWS];

  int tid = threadIdx.x;
  int base = blockIdx.x * ROWS;

  for (int i = tid; i < 3 * NDESC; i += NTHREADS) sW[i] = W[i];
  if (tid < ROWS) {
    int p = base + tid;
    uint32 a = (p < n) ? perm[p] : 0u;
    sPerm[tid] = a;
    if (p < n) confOut[p] = (float)(a >> 6);   // atom / 64 atoms-per-conf
  }
  __syncthreads();
  if (tid < ROWS * 3) {
    int rrow = tid / 3, comp = tid - 3 * rrow;
    sC[rrow][comp] = (base + rrow < n)
                         ? coords[(size_t)sPerm[rrow] * 3 + comp] : 0.0f;
  }
  __syncthreads();

  int r = tid / 96;        // row slot 0..3
  int c = tid - r * 96;    // 0..95
  int d0 = 4 * c;
  float w00 = sW[d0], w01 = sW[d0 + 1], w02 = sW[d0 + 2], w03 = sW[d0 + 3];
  float w10 = sW[NDESC + d0], w11 = sW[NDESC + d0 + 1],
        w12 = sW[NDESC + d0 + 2], w13 = sW[NDESC + d0 + 3];
  float w20 = sW[2 * NDESC + d0], w21 = sW[2 * NDESC + d0 + 1],
        w22 = sW[2 * NDESC + d0 + 2], w23 = sW[2 * NDESC + d0 + 3];

  int valid = n - base;
  if (valid > ROWS) valid = ROWS;

  if (valid == ROWS) {
#pragma unroll 4
    for (int k0 = 0; k0 < ROWS; k0 += 4) {
      int k = k0 + r;
      float c0 = sC[k][0], c1 = sC[k][1], c2 = sC[k][2];
      f4 v;
      v.x = fast_tanh(c0 * w00 + c1 * w10 + c2 * w20);
      v.y = fast_tanh(c0 * w01 + c1 * w11 + c2 * w21);
      v.z = fast_tanh(c0 * w02 + c1 * w12 + c2 * w22);
      v.w = fast_tanh(c0 * w03 + c1 * w13 + c2 * w23);
      *reinterpret_cast<f4*>(descOut + (size_t)(base + k) * NDESC + d0) = v;
    }
  } else {
    for (int k0 = 0; k0 < ROWS; k0 += 4) {
      int k = k0 + r;
      if (k < valid) {
        float c0 = sC[k][0], c1 = sC[k][1], c2 = sC[k][2];
        f4 v;
        v.x = fast_tanh(c0 * w00 + c1 * w10 + c2 * w20);
        v.y = fast_tanh(c0 * w01 + c1 * w11 + c2 * w21);
        v.z = fast_tanh(c0 * w02 + c1 * w12 + c2 * w22);
        v.w = fast_tanh(c0 * w03 + c1 * w13 + c2 * w23);
        *reinterpret_cast<f4*>(descOut + (size_t)(base + k) * NDESC + d0) = v;
      }
    }
  }
}

extern "C" void kernel_launch(void* const* d_in, const int* in_sizes, int n_in,
                              void* d_out, int out_size, void* d_ws, size_t ws_size,
                              hipStream_t stream) {
  const float* coords = (const float*)d_in[0];
  const int* types = (const int*)d_in[1];
  const float* W = (const float*)d_in[2];

  int n = in_sizes[1];                      // total atoms (= n_confs * 64)
  int nb = (n + BLOCK_ATOMS - 1) / BLOCK_ATOMS;
  int ngb = (n + ROWS - 1) / ROWS;

  uint32* blockHist = (uint32*)d_ws;                     // nb*4 uints
  uint32* perm = blockHist + (size_t)nb * NTYPES;        // n uints

  float* descOut = (float*)d_out;
  float* confOut = descOut + (size_t)n * NDESC;
  float* countsOut = confOut + n;

  hipLaunchKernelGGL(hist_kernel, dim3(nb), dim3(BLOCK_ATOMS), 0, stream,
                     types, blockHist, n);
  hipLaunchKernelGGL(perm_kernel, dim3(nb), dim3(BLOCK_ATOMS), 0, stream,
                     types, blockHist, perm, countsOut, n, nb);
  hipLaunchKernelGGL(gather_kernel, dim3(ngb), dim3(NTHREADS), 0, stream,
                     coords, perm, W, descOut, confOut, n);
}

// Round 9
// 46.670 us; speedup vs baseline: 1.1509x; 1.0369x over previous
//
#include <hip/hip_runtime.h>

#define NDESC 384
#define NTYPES 4
#define BLOCK_ATOMS 256
#define NTHREADS 384

typedef unsigned int uint32;
typedef unsigned long long u64;
typedef float f4 __attribute__((ext_vector_type(4)));

// tanh(x) = 1 - 2/(1+e^{2x}); native v_exp_f32 + v_rcp_f32. Abs err ~1e-6.
__device__ __forceinline__ float fast_tanh(float x) {
  float e = __builtin_amdgcn_exp2f(x * 2.8853900817779268f);   // e^{2x}
  return 1.0f - 2.0f * __builtin_amdgcn_rcpf(1.0f + e);
}

// ---------------- Kernel 1: per-block type histogram (ballot-based) --------
__global__ __launch_bounds__(BLOCK_ATOMS) void hist_kernel(
    const int* __restrict__ types, uint32* __restrict__ blockHist, int n) {
  __shared__ uint32 waveCnt[BLOCK_ATOMS / 64][NTYPES];
  int tid = threadIdx.x;
  int idx = blockIdx.x * BLOCK_ATOMS + tid;
  int ty = (idx < n) ? types[idx] : -1;
  int wave = tid >> 6, lane = tid & 63;
  for (int t = 0; t < NTYPES; ++t) {
    u64 m = __ballot(ty == t);
    if (lane == 0) waveCnt[wave][t] = (uint32)__popcll(m);
  }
  __syncthreads();
  if (tid < NTYPES) {
    uint32 s = 0;
    for (int w = 0; w < BLOCK_ATOMS / 64; ++w) s += waveCnt[w][tid];
    blockHist[blockIdx.x * NTYPES + tid] = s;
  }
}

// ---------------- Kernel 2: fused scan + rank + descriptor + scatter -------
// launch_bounds(384,6): VGPR<=~84 -> 4 blocks/CU (24 waves) for overlap.
// W loaded straight into registers (3x float4, issued at kernel top, L2-hot).
// Phase C iterates in RANK order: 4 monotone write streams per block.
__global__ __launch_bounds__(NTHREADS, 6) void main_kernel(
    const float* __restrict__ coords, const int* __restrict__ types,
    const float* __restrict__ W, const uint32* __restrict__ blockHist,
    float* __restrict__ descOut, float* __restrict__ confOut,
    float* __restrict__ countsOut, int n, int nb) {
  __shared__ float sC[BLOCK_ATOMS][3];
  __shared__ uint32 sRankPos[BLOCK_ATOMS];   // block-rank -> global position
  __shared__ uint32 sRankAtom[BLOCK_ATOMS];  // block-rank -> atom tid
  __shared__ uint32 waveCnt[BLOCK_ATOMS / 64][NTYPES];
  __shared__ uint32 sTot[NTYPES];   // global per-type totals
  __shared__ uint32 sOff[NTYPES];   // this block's global base per type
  __shared__ uint32 sCum[NTYPES];   // within-block exclusive type prefix

  int tid = threadIdx.x;
  int bid = blockIdx.x;
  int base = bid * BLOCK_ATOMS;

  // phase-C thread mapping, needed now for the early W loads
  int r = tid / 96;        // rank slot 0..3
  int c = tid - r * 96;    // 0..95
  int d0 = 4 * c;

  // early W register loads — in flight during ballots/scan below
  f4 W0 = *reinterpret_cast<const f4*>(W + d0);
  f4 W1 = *reinterpret_cast<const f4*>(W + NDESC + d0);
  f4 W2 = *reinterpret_cast<const f4*>(W + 2 * NDESC + d0);

  // stage this block's coords (256x3)
  for (int i = tid; i < BLOCK_ATOMS * 3; i += NTHREADS) {
    int g = base * 3 + i;
    sC[i / 3][i % 3] = (g < n * 3) ? coords[g] : 0.0f;
  }

  // ---- ballots: within-block per-wave counts + per-lane stable rank ----
  int idx = base + tid;
  int ty = -1;
  if (tid < BLOCK_ATOMS && idx < n) ty = types[idx];
  int wave = tid >> 6, lane = tid & 63;
  int myrank = 0;
  if (tid < BLOCK_ATOMS) {
    for (int t = 0; t < NTYPES; ++t) {
      u64 m = __ballot(ty == t);
      if (lane == 0) waveCnt[wave][t] = (uint32)__popcll(m);
      if (t == ty) myrank = (int)__popcll(m & ((1ull << lane) - 1ull));
    }
  }

  // ---- per-block scan of blockHist: wave t handles type t ----
  if (wave < NTYPES) {
    int t = wave;
    uint32 tot = 0, pre = 0;
    for (int b = lane; b < nb; b += 64) {
      uint32 h = blockHist[b * NTYPES + t];
      tot += h;
      if (b < bid) pre += h;
    }
    for (int off = 32; off > 0; off >>= 1) {
      tot += __shfl_down(tot, off);
      pre += __shfl_down(pre, off);
    }
    if (lane == 0) { sTot[t] = tot; sOff[t] = pre; }
  }
  __syncthreads();
  if (tid == 0) {
    uint32 b = 0, cc = 0;
    for (int t = 0; t < NTYPES; ++t) {
      sOff[t] += b;
      b += sTot[t];
      uint32 cnt = 0;
      for (int w = 0; w < BLOCK_ATOMS / 64; ++w) cnt += waveCnt[w][t];
      sCum[t] = cc;
      cc += cnt;
    }
  }
  if (bid == 0 && tid < NTYPES) countsOut[tid] = (float)sTot[tid];
  __syncthreads();

  // ---- scatter rank tables + conf ids ----
  if (tid < BLOCK_ATOMS && ty >= 0) {
    uint32 fullrank = (uint32)myrank;
    for (int w = 0; w < wave; ++w) fullrank += waveCnt[w][ty];
    uint32 pos = sOff[ty] + fullrank;
    uint32 brk = sCum[ty] + fullrank;   // rank within block, 0..valid-1
    sRankPos[brk] = pos;
    sRankAtom[brk] = (uint32)tid;
    confOut[pos] = (float)(idx >> 6);   // idx / 64 atoms-per-conf
  }
  __syncthreads();

  // ---- phase C: rank order, 4 ranks x 96 threads, plain f4 stores ----
  int valid = n - base;
  if (valid > BLOCK_ATOMS) valid = BLOCK_ATOMS;

  if (valid == BLOCK_ATOMS) {
#pragma unroll 4
    for (int k0 = 0; k0 < BLOCK_ATOMS; k0 += 4) {
      int k = k0 + r;
      uint32 a = sRankAtom[k];
      uint32 pos = sRankPos[k];
      float c0 = sC[a][0], c1 = sC[a][1], c2 = sC[a][2];
      f4 v;
      v.x = fast_tanh(c0 * W0.x + c1 * W1.x + c2 * W2.x);
      v.y = fast_tanh(c0 * W0.y + c1 * W1.y + c2 * W2.y);
      v.z = fast_tanh(c0 * W0.z + c1 * W1.z + c2 * W2.z);
      v.w = fast_tanh(c0 * W0.w + c1 * W1.w + c2 * W2.w);
      *reinterpret_cast<f4*>(descOut + (size_t)pos * NDESC + d0) = v;
    }
  } else {
    for (int k0 = 0; k0 < BLOCK_ATOMS; k0 += 4) {
      int k = k0 + r;
      if (k < valid) {
        uint32 a = sRankAtom[k];
        uint32 pos = sRankPos[k];
        float c0 = sC[a][0], c1 = sC[a][1], c2 = sC[a][2];
        f4 v;
        v.x = fast_tanh(c0 * W0.x + c1 * W1.x + c2 * W2.x);
        v.y = fast_tanh(c0 * W0.y + c1 * W1.y + c2 * W2.y);
        v.z = fast_tanh(c0 * W0.z + c1 * W1.z + c2 * W2.z);
        v.w = fast_tanh(c0 * W0.w + c1 * W1.w + c2 * W2.w);
        *reinterpret_cast<f4*>(descOut + (size_t)pos * NDESC + d0) = v;
      }
    }
  }
}

extern "C" void kernel_launch(void* const* d_in, const int* in_sizes, int n_in,
                              void* d_out, int out_size, void* d_ws, size_t ws_size,
                              hipStream_t stream) {
  const float* coords = (const float*)d_in[0];
  const int* types = (const int*)d_in[1];
  const float* W = (const float*)d_in[2];

  int n = in_sizes[1];                      // total atoms (= n_confs * 64)
  int nb = (n + BLOCK_ATOMS - 1) / BLOCK_ATOMS;

  uint32* blockHist = (uint32*)d_ws;        // nb * 4 uints

  float* descOut = (float*)d_out;
  float* confOut = descOut + (size_t)n * NDESC;
  float* countsOut = confOut + n;

  hipLaunchKernelGGL(hist_kernel, dim3(nb), dim3(BLOCK_ATOMS), 0, stream,
                     types, blockHist, n);
  hipLaunchKernelGGL(main_kernel, dim3(nb), dim3(NTHREADS), 0, stream,
                     coords, types, W, blockHist, descOut, confOut, countsOut,
                     n, nb);
}

// Round 10
// 46.102 us; speedup vs baseline: 1.1651x; 1.0123x over previous
//
#include <hip/hip_runtime.h>

#define NDESC 384
#define NTYPES 4
#define BLOCK_ATOMS 256
#define NTHREADS 384

typedef unsigned int uint32;
typedef unsigned long long u64;
typedef float f4 __attribute__((ext_vector_type(4)));

// tanh(x) = 1 - 2/(1+e^{2x}); native v_exp_f32 + v_rcp_f32. Abs err ~1e-6.
__device__ __forceinline__ float fast_tanh(float x) {
  float e = __builtin_amdgcn_exp2f(x * 2.8853900817779268f);   // e^{2x}
  return 1.0f - 2.0f * __builtin_amdgcn_rcpf(1.0f + e);
}

// ---------------- Kernel 1: per-block type histogram (ballot-based) --------
__global__ __launch_bounds__(BLOCK_ATOMS) void hist_kernel(
    const int* __restrict__ types, uint32* __restrict__ blockHist, int n) {
  __shared__ uint32 waveCnt[BLOCK_ATOMS / 64][NTYPES];
  int tid = threadIdx.x;
  int idx = blockIdx.x * BLOCK_ATOMS + tid;
  int ty = (idx < n) ? types[idx] : -1;
  int wave = tid >> 6, lane = tid & 63;
  for (int t = 0; t < NTYPES; ++t) {
    u64 m = __ballot(ty == t);
    if (lane == 0) waveCnt[wave][t] = (uint32)__popcll(m);
  }
  __syncthreads();
  if (tid < NTYPES) {
    uint32 s = 0;
    for (int w = 0; w < BLOCK_ATOMS / 64; ++w) s += waveCnt[w][tid];
    blockHist[blockIdx.x * NTYPES + tid] = s;
  }
}

// ---------------- Kernel 2: fused scan + rank + descriptor + scatter -------
// Phase C reads ONE packed f4 {c0,c1,c2,pos} per rank via ds_read_b128
// (broadcast) instead of 5 scalar b32 reads — removes ~8 us of LDS-pipe
// serialization from the store critical path.
__global__ __launch_bounds__(NTHREADS, 6) void main_kernel(
    const float* __restrict__ coords, const int* __restrict__ types,
    const float* __restrict__ W, const uint32* __restrict__ blockHist,
    float* __restrict__ descOut, float* __restrict__ confOut,
    float* __restrict__ countsOut, int n, int nb) {
  __shared__ float sC[BLOCK_ATOMS][3];
  __shared__ f4 sRankData[BLOCK_ATOMS];      // block-rank -> {c0,c1,c2,pos}
  __shared__ uint32 waveCnt[BLOCK_ATOMS / 64][NTYPES];
  __shared__ uint32 sTot[NTYPES];   // global per-type totals
  __shared__ uint32 sOff[NTYPES];   // this block's global base per type
  __shared__ uint32 sCum[NTYPES];   // within-block exclusive type prefix

  int tid = threadIdx.x;
  int bid = blockIdx.x;
  int base = bid * BLOCK_ATOMS;

  // phase-C thread mapping, needed now for the early W loads
  int r = tid / 96;        // rank slot 0..3
  int c = tid - r * 96;    // 0..95
  int d0 = 4 * c;

  // early W register loads — in flight during ballots/scan below
  f4 W0 = *reinterpret_cast<const f4*>(W + d0);
  f4 W1 = *reinterpret_cast<const f4*>(W + NDESC + d0);
  f4 W2 = *reinterpret_cast<const f4*>(W + 2 * NDESC + d0);

  // stage this block's coords (256x3) coalesced
  for (int i = tid; i < BLOCK_ATOMS * 3; i += NTHREADS) {
    int g = base * 3 + i;
    sC[i / 3][i % 3] = (g < n * 3) ? coords[g] : 0.0f;
  }

  // ---- ballots: within-block per-wave counts + per-lane stable rank ----
  int idx = base + tid;
  int ty = -1;
  if (tid < BLOCK_ATOMS && idx < n) ty = types[idx];
  int wave = tid >> 6, lane = tid & 63;
  int myrank = 0;
  if (tid < BLOCK_ATOMS) {
    for (int t = 0; t < NTYPES; ++t) {
      u64 m = __ballot(ty == t);
      if (lane == 0) waveCnt[wave][t] = (uint32)__popcll(m);
      if (t == ty) myrank = (int)__popcll(m & ((1ull << lane) - 1ull));
    }
  }

  // ---- per-block scan of blockHist: wave t handles type t ----
  if (wave < NTYPES) {
    int t = wave;
    uint32 tot = 0, pre = 0;
    for (int b = lane; b < nb; b += 64) {
      uint32 h = blockHist[b * NTYPES + t];
      tot += h;
      if (b < bid) pre += h;
    }
    for (int off = 32; off > 0; off >>= 1) {
      tot += __shfl_down(tot, off);
      pre += __shfl_down(pre, off);
    }
    if (lane == 0) { sTot[t] = tot; sOff[t] = pre; }
  }
  __syncthreads();
  if (tid == 0) {
    uint32 b = 0, cc = 0;
    for (int t = 0; t < NTYPES; ++t) {
      sOff[t] += b;
      b += sTot[t];
      uint32 cnt = 0;
      for (int w = 0; w < BLOCK_ATOMS / 64; ++w) cnt += waveCnt[w][t];
      sCum[t] = cc;
      cc += cnt;
    }
  }
  if (bid == 0 && tid < NTYPES) countsOut[tid] = (float)sTot[tid];
  __syncthreads();

  // ---- scatter packed rank data + conf ids ----
  if (tid < BLOCK_ATOMS && ty >= 0) {
    uint32 fullrank = (uint32)myrank;
    for (int w = 0; w < wave; ++w) fullrank += waveCnt[w][ty];
    uint32 pos = sOff[ty] + fullrank;
    uint32 brk = sCum[ty] + fullrank;   // rank within block, 0..valid-1
    f4 rd;
    rd.x = sC[tid][0];
    rd.y = sC[tid][1];
    rd.z = sC[tid][2];
    rd.w = __uint_as_float(pos);
    sRankData[brk] = rd;
    confOut[pos] = (float)(idx >> 6);   // idx / 64 atoms-per-conf
  }
  __syncthreads();

  // ---- phase C: rank order, 4 ranks x 96 threads, one b128 read/iter ----
  int valid = n - base;
  if (valid > BLOCK_ATOMS) valid = BLOCK_ATOMS;

  if (valid == BLOCK_ATOMS) {
#pragma unroll 4
    for (int k0 = 0; k0 < BLOCK_ATOMS; k0 += 4) {
      int k = k0 + r;
      f4 rd = sRankData[k];
      uint32 pos = __float_as_uint(rd.w);
      f4 v;
      v.x = fast_tanh(rd.x * W0.x + rd.y * W1.x + rd.z * W2.x);
      v.y = fast_tanh(rd.x * W0.y + rd.y * W1.y + rd.z * W2.y);
      v.z = fast_tanh(rd.x * W0.z + rd.y * W1.z + rd.z * W2.z);
      v.w = fast_tanh(rd.x * W0.w + rd.y * W1.w + rd.z * W2.w);
      *reinterpret_cast<f4*>(descOut + (size_t)pos * NDESC + d0) = v;
    }
  } else {
    for (int k0 = 0; k0 < BLOCK_ATOMS; k0 += 4) {
      int k = k0 + r;
      if (k < valid) {
        f4 rd = sRankData[k];
        uint32 pos = __float_as_uint(rd.w);
        f4 v;
        v.x = fast_tanh(rd.x * W0.x + rd.y * W1.x + rd.z * W2.x);
        v.y = fast_tanh(rd.x * W0.y + rd.y * W1.y + rd.z * W2.y);
        v.z = fast_tanh(rd.x * W0.z + rd.y * W1.z + rd.z * W2.z);
        v.w = fast_tanh(rd.x * W0.w + rd.y * W1.w + rd.z * W2.w);
        *reinterpret_cast<f4*>(descOut + (size_t)pos * NDESC + d0) = v;
      }
    }
  }
}

extern "C" void kernel_launch(void* const* d_in, const int* in_sizes, int n_in,
                              void* d_out, int out_size, void* d_ws, size_t ws_size,
                              hipStream_t stream) {
  const float* coords = (const float*)d_in[0];
  const int* types = (const int*)d_in[1];
  const float* W = (const float*)d_in[2];

  int n = in_sizes[1];                      // total atoms (= n_confs * 64)
  int nb = (n + BLOCK_ATOMS - 1) / BLOCK_ATOMS;

  uint32* blockHist = (uint32*)d_ws;        // nb * 4 uints

  float* descOut = (float*)d_out;
  float* confOut = descOut + (size_t)n * NDESC;
  float* countsOut = confOut + n;

  hipLaunchKernelGGL(hist_kernel, dim3(nb), dim3(BLOCK_ATOMS), 0, stream,
                     types, blockHist, n);
  hipLaunchKernelGGL(main_kernel, dim3(nb), dim3(NTHREADS), 0, stream,
                     coords, types, W, blockHist, descOut, confOut, countsOut,
                     n, nb);
}

// Round 11
// 45.602 us; speedup vs baseline: 1.1779x; 1.0110x over previous
//
#include <hip/hip_runtime.h>

#define NDESC 384
#define NTYPES 4
#define BLOCK_ATOMS 256
#define NTHREADS 512
#define NPROD 384                         // 6 producer waves
#define TILE_ROWS 16
#define NTILES (BLOCK_ATOMS / TILE_ROWS)  // 16
#define TILE_F4 (TILE_ROWS * NDESC / 4)   // 1536 f4 per tile

typedef unsigned int uint32;
typedef unsigned long long u64;
typedef float f4 __attribute__((ext_vector_type(4)));

// tanh(x) = 1 - 2/(1+e^{2x}); native v_exp_f32 + v_rcp_f32. Abs err ~1e-6.
__device__ __forceinline__ float fast_tanh(float x) {
  float e = __builtin_amdgcn_exp2f(x * 2.8853900817779268f);   // e^{2x}
  return 1.0f - 2.0f * __builtin_amdgcn_rcpf(1.0f + e);
}

// ---------------- Kernel 1: per-block type histogram (ballot-based) --------
__global__ __launch_bounds__(BLOCK_ATOMS) void hist_kernel(
    const int* __restrict__ types, uint32* __restrict__ blockHist, int n) {
  __shared__ uint32 waveCnt[BLOCK_ATOMS / 64][NTYPES];
  int tid = threadIdx.x;
  int idx = blockIdx.x * BLOCK_ATOMS + tid;
  int ty = (idx < n) ? types[idx] : -1;
  int wave = tid >> 6, lane = tid & 63;
  for (int t = 0; t < NTYPES; ++t) {
    u64 m = __ballot(ty == t);
    if (lane == 0) waveCnt[wave][t] = (uint32)__popcll(m);
  }
  __syncthreads();
  if (tid < NTYPES) {
    uint32 s = 0;
    for (int w = 0; w < BLOCK_ATOMS / 64; ++w) s += waveCnt[w][tid];
    blockHist[blockIdx.x * NTYPES + tid] = s;
  }
}

// ---------------- Kernel 2: producer/consumer main kernel ------------------
// 8 waves: 6 compute tanh tiles into double-buffered LDS; 2 run a pure
// ds_read_b128 -> global_store_dwordx4 stream (fill-kernel-shaped), so the
// store pipe is fed continuously while compute rides in other waves.
__global__ __launch_bounds__(NTHREADS, 4) void main_kernel(
    const float* __restrict__ coords, const int* __restrict__ types,
    const float* __restrict__ W, const uint32* __restrict__ blockHist,
    float* __restrict__ descOut, float* __restrict__ confOut,
    float* __restrict__ countsOut, int n, int nb) {
  __shared__ f4 tileBuf[2][TILE_F4];         // 48 KB double buffer
  __shared__ float sC[BLOCK_ATOMS][3];
  __shared__ f4 sRankData[BLOCK_ATOMS];      // rank -> {c0,c1,c2,pos}
  __shared__ uint32 waveCnt[BLOCK_ATOMS / 64][NTYPES];
  __shared__ uint32 sTot[NTYPES];
  __shared__ uint32 sOff[NTYPES];
  __shared__ uint32 sCum[NTYPES];

  int tid = threadIdx.x;
  int bid = blockIdx.x;
  int base = bid * BLOCK_ATOMS;

  // producer column mapping (tid 0..383): col ct, descriptor cols [4ct,4ct+4)
  int ct = tid % 96;
  int d0p = 4 * ct;
  f4 W0 = *reinterpret_cast<const f4*>(W + d0p);
  f4 W1 = *reinterpret_cast<const f4*>(W + NDESC + d0p);
  f4 W2 = *reinterpret_cast<const f4*>(W + 2 * NDESC + d0p);

  // stage this block's coords (256x3) coalesced
  for (int i = tid; i < BLOCK_ATOMS * 3; i += NTHREADS) {
    int g = base * 3 + i;
    sC[i / 3][i % 3] = (g < n * 3) ? coords[g] : 0.0f;
  }

  // ---- ballots (waves 0..3): per-wave counts + stable rank ----
  int idx = base + tid;
  int ty = -1;
  if (tid < BLOCK_ATOMS && idx < n) ty = types[idx];
  int wave = tid >> 6, lane = tid & 63;
  int myrank = 0;
  if (tid < BLOCK_ATOMS) {
    for (int t = 0; t < NTYPES; ++t) {
      u64 m = __ballot(ty == t);
      if (lane == 0) waveCnt[wave][t] = (uint32)__popcll(m);
      if (t == ty) myrank = (int)__popcll(m & ((1ull << lane) - 1ull));
    }
  }

  // ---- per-block scan of blockHist: wave t handles type t ----
  if (wave < NTYPES) {
    int t = wave;
    uint32 tot = 0, pre = 0;
    for (int b = lane; b < nb; b += 64) {
      uint32 h = blockHist[b * NTYPES + t];
      tot += h;
      if (b < bid) pre += h;
    }
    for (int off = 32; off > 0; off >>= 1) {
      tot += __shfl_down(tot, off);
      pre += __shfl_down(pre, off);
    }
    if (lane == 0) { sTot[t] = tot; sOff[t] = pre; }
  }
  __syncthreads();
  if (tid == 0) {
    uint32 b = 0, cc = 0;
    for (int t = 0; t < NTYPES; ++t) {
      sOff[t] += b;
      b += sTot[t];
      uint32 cnt = 0;
      for (int w = 0; w < BLOCK_ATOMS / 64; ++w) cnt += waveCnt[w][t];
      sCum[t] = cc;
      cc += cnt;
    }
  }
  if (bid == 0 && tid < NTYPES) countsOut[tid] = (float)sTot[tid];
  __syncthreads();

  // ---- scatter packed rank data + conf ids ----
  if (tid < BLOCK_ATOMS && ty >= 0) {
    uint32 fullrank = (uint32)myrank;
    for (int w = 0; w < wave; ++w) fullrank += waveCnt[w][ty];
    uint32 pos = sOff[ty] + fullrank;
    uint32 brk = sCum[ty] + fullrank;
    f4 rd;
    rd.x = sC[tid][0];
    rd.y = sC[tid][1];
    rd.z = sC[tid][2];
    rd.w = __uint_as_float(pos);
    sRankData[brk] = rd;
    confOut[pos] = (float)(idx >> 6);   // idx / 64 atoms-per-conf
  }
  __syncthreads();

  int valid = n - base;
  if (valid > BLOCK_ATOMS) valid = BLOCK_ATOMS;

  if (valid == BLOCK_ATOMS) {
    bool producer = (tid < NPROD);
    int rbase = tid / 96;   // 0..3 (producers)

    // prologue: fill tile 0 into buf 0
    if (producer) {
#pragma unroll
      for (int k = 0; k < 4; ++k) {
        int rrow = rbase + k * 4;              // tile-local row 0..15
        f4 rd = sRankData[rrow];
        f4 v;
        v.x = fast_tanh(rd.x * W0.x + rd.y * W1.x + rd.z * W2.x);
        v.y = fast_tanh(rd.x * W0.y + rd.y * W1.y + rd.z * W2.y);
        v.z = fast_tanh(rd.x * W0.z + rd.y * W1.z + rd.z * W2.z);
        v.w = fast_tanh(rd.x * W0.w + rd.y * W1.w + rd.z * W2.w);
        tileBuf[0][k * NPROD + tid] = v;       // index == row*96 + col
      }
    }
    __syncthreads();

    for (int tl = 0; tl < NTILES; ++tl) {
      int cur = tl & 1;
      if (producer) {
        if (tl + 1 < NTILES) {
          int tbase = (tl + 1) * TILE_ROWS;
#pragma unroll
          for (int k = 0; k < 4; ++k) {
            int rrow = tbase + rbase + k * 4;
            f4 rd = sRankData[rrow];
            f4 v;
            v.x = fast_tanh(rd.x * W0.x + rd.y * W1.x + rd.z * W2.x);
            v.y = fast_tanh(rd.x * W0.y + rd.y * W1.y + rd.z * W2.y);
            v.z = fast_tanh(rd.x * W0.z + rd.y * W1.z + rd.z * W2.z);
            v.w = fast_tanh(rd.x * W0.w + rd.y * W1.w + rd.z * W2.w);
            tileBuf[cur ^ 1][k * NPROD + tid] = v;
          }
        }
      } else {
        int u = tid - NPROD;                   // 0..127, pure store stream
#pragma unroll
        for (int k = 0; k < 12; ++k) {
          int j = k * 128 + u;                 // 0..1535
          int rr = j / 96;                     // tile-local row
          int col = j - rr * 96;
          uint32 pos = __float_as_uint(sRankData[tl * TILE_ROWS + rr].w);
          f4 v = tileBuf[cur][j];
          *reinterpret_cast<f4*>(descOut + (size_t)pos * NDESC + 4 * col) = v;
        }
      }
      __syncthreads();
    }
  } else {
    // fallback for partial blocks (not hit at n = multiple of 256)
    if (tid < NPROD) {
      for (int k0 = 0; k0 < BLOCK_ATOMS; k0 += 4) {
        int k = k0 + tid / 96;
        if (k < valid) {
          f4 rd = sRankData[k];
          uint32 pos = __float_as_uint(rd.w);
          f4 v;
          v.x = fast_tanh(rd.x * W0.x + rd.y * W1.x + rd.z * W2.x);
          v.y = fast_tanh(rd.x * W0.y + rd.y * W1.y + rd.z * W2.y);
          v.z = fast_tanh(rd.x * W0.z + rd.y * W1.z + rd.z * W2.z);
          v.w = fast_tanh(rd.x * W0.w + rd.y * W1.w + rd.z * W2.w);
          *reinterpret_cast<f4*>(descOut + (size_t)pos * NDESC + d0p) = v;
        }
      }
    }
  }
}

extern "C" void kernel_launch(void* const* d_in, const int* in_sizes, int n_in,
                              void* d_out, int out_size, void* d_ws, size_t ws_size,
                              hipStream_t stream) {
  const float* coords = (const float*)d_in[0];
  const int* types = (const int*)d_in[1];
  const float* W = (const float*)d_in[2];

  int n = in_sizes[1];                      // total atoms (= n_confs * 64)
  int nb = (n + BLOCK_ATOMS - 1) / BLOCK_ATOMS;

  uint32* blockHist = (uint32*)d_ws;        // nb * 4 uints

  float* descOut = (float*)d_out;
  float* confOut = descOut + (size_t)n * NDESC;
  float* countsOut = confOut + n;

  hipLaunchKernelGGL(hist_kernel, dim3(nb), dim3(BLOCK_ATOMS), 0, stream,
                     types, blockHist, n);
  hipLaunchKernelGGL(main_kernel, dim3(nb), dim3(NTHREADS), 0, stream,
                     coords, types, W, blockHist, descOut, confOut, countsOut,
                     n, nb);
}